// Round 3
// baseline (1363.174 us; speedup 1.0000x reference)
//
#include <hip/hip_runtime.h>
#include <math.h>

#define TT 1024
#define BB 16
#define CC 1024
#define HH 16
#define KK 7
#define PADL 6
#define HK 112        // H*K
#define WSTRIDE 68    // LDS row stride in floats: 272 B (16B-aligned), even bank spread

typedef float vf4 __attribute__((ext_vector_type(4)));

// ---------------------------------------------------------------------------
// K1: logits = x @ W^T, band-masked softmax -> wsm[t,b,h,k].
// 128 threads: tx = tid&15 -> head (owns all 7 taps => thread-local softmax)
//              ty = tid>>4 -> 4-row group; block covers 32 (t,b) rows.
// W staged per 64-channel chunk into double-buffered LDS (one barrier/chunk,
// prefetch of chunk c+1 overlaps compute of chunk c). 4 rows/thread amortizes
// each ds_read_b128 of W over 16 fmacs -> per-CU LDS traffic halves vs r2.
// grid = (T*B)/32 = 512 blocks.
// ---------------------------------------------------------------------------
__device__ __forceinline__ void stage_chunk(const float* __restrict__ W,
                                            float* __restrict__ buf,
                                            int c0, int tid) {
    // 112 rows x 64 floats = 7168 floats = 1792 float4; 128 threads x 14 each
#pragma unroll
    for (int j = 0; j < 14; ++j) {
        const int i = j * 512 + tid * 4;
        const int o = i >> 6;        // 0..111
        const int c = i & 63;        // float4-aligned
        const float4 v = *(const float4*)(W + (size_t)o * CC + c0 + c);
        *(float4*)(&buf[o * WSTRIDE + c]) = v;
    }
}

__global__ __launch_bounds__(128) void k1_weights(const float* __restrict__ x,
                                                  const float* __restrict__ W,
                                                  float* __restrict__ wsm) {
    __shared__ float Wl[2][HK * WSTRIDE];   // 2 x 29.75 KB = 59.5 KB

    const int tid = threadIdx.x;
    const int tx = tid & 15;        // head
    const int ty = tid >> 4;        // 0..7
    const int row0 = blockIdx.x * 32 + ty * 4;   // (t*B + b) flat row

    const float* __restrict__ xr0 = x + (size_t)row0 * CC;

    float acc[4][KK];
#pragma unroll
    for (int i = 0; i < 4; ++i)
#pragma unroll
        for (int k = 0; k < KK; ++k) acc[i][k] = 0.f;

    stage_chunk(W, Wl[0], 0, tid);
    __syncthreads();

    for (int ch = 0; ch < 16; ++ch) {
        const int p = ch & 1;
        const int c0 = ch * 64;
        if (ch + 1 < 16) stage_chunk(W, Wl[p ^ 1], c0 + 64, tid);

        const float* __restrict__ Wb = &Wl[p][(tx * KK) * WSTRIDE];
#pragma unroll 2
        for (int c = 0; c < 64; c += 4) {
            float4 xv[4];
#pragma unroll
            for (int i = 0; i < 4; ++i)
                xv[i] = *(const float4*)(xr0 + (size_t)i * CC + c0 + c);
#pragma unroll
            for (int k = 0; k < KK; ++k) {
                const float4 wv = *(const float4*)(Wb + k * WSTRIDE + c);
#pragma unroll
                for (int i = 0; i < 4; ++i)
                    acc[i][k] += xv[i].x * wv.x + xv[i].y * wv.y +
                                 xv[i].z * wv.z + xv[i].w * wv.w;
            }
        }
        __syncthreads();
    }

#pragma unroll
    for (int i = 0; i < 4; ++i) {
        const float* a = acc[i];
        const int row = row0 + i;
        const int t = row >> 4;                    // row = t*B + b
        const int kmin = (t >= PADL) ? 0 : (PADL - t);

        float m = -INFINITY;
#pragma unroll
        for (int k = 0; k < KK; ++k)
            if (k >= kmin) m = fmaxf(m, a[k]);

        float e[KK];
        float s = 0.f;
#pragma unroll
        for (int k = 0; k < KK; ++k) {
            if (k >= kmin) { e[k] = expf(a[k] - m); s += e[k]; }
            else           { e[k] = 0.f; }
        }
        const float inv = 1.f / s;
        float* __restrict__ wp = wsm + (((size_t)row * HH) + tx) * KK;
#pragma unroll
        for (int k = 0; k < KK; ++k) wp[k] = e[k] * inv;
    }
}

// ---------------------------------------------------------------------------
// K2: stream the full dense (B*H, T, T) band matrix. One block per
// (bh, 16-row t-chunk): 256 threads x 16 rows x float4 = 64 KB contiguous.
// Nontemporal stores: dense is write-once, never re-read.
// grid = B*H*(T/16) = 16384 blocks.
// ---------------------------------------------------------------------------
__global__ __launch_bounds__(256) void k2_dense(const float* __restrict__ wsm,
                                                float* __restrict__ dense) {
    const int blk = blockIdx.x;        // bh*64 + tc
    const int bh = blk >> 6;
    const int tc = blk & 63;           // t-chunk
    const int b = bh >> 4;
    const int h = bh & 15;

    const int col = threadIdx.x << 2;
    const int t0 = tc * 16;

    float* __restrict__ drow = dense + ((size_t)bh * TT + t0) * TT + col;

#pragma unroll
    for (int i = 0; i < 16; ++i) {
        const int t = t0 + i;
        const int lo = t - PADL;       // may be negative
        vf4 v = (vf4){0.f, 0.f, 0.f, 0.f};
        if (col + 3 >= lo && col <= t) {
            const float* __restrict__ wp =
                wsm + (((size_t)t * BB + b) * HH + h) * KK;
#pragma unroll
            for (int j = 0; j < 4; ++j) {
                const int cc = col + j;
                if (cc >= lo && cc <= t && cc >= 0) v[j] = wp[cc - lo];
            }
        }
        __builtin_nontemporal_store(v, (vf4*)drow);
        drow += TT;
    }
}

// ---------------------------------------------------------------------------
// K3: out[t,b,c] = sum_k wsm[t,b,h,k] * x[t+k-6, b, c],  h = c/64.
// One block per 8 (t,b) rows (same t since 8 | 16), 256 threads x float4.
// grid = T*B/8 = 2048 blocks.
// ---------------------------------------------------------------------------
__global__ __launch_bounds__(256) void k3_out(const float* __restrict__ x,
                                              const float* __restrict__ wsm,
                                              float* __restrict__ out) {
    const int r0 = blockIdx.x << 3;    // flat row = t*B + b; 8 rows share t
    const int t = r0 >> 4;
    const int c = threadIdx.x << 2;
    const int h = c >> 6;
    const int kmin = (t >= PADL) ? 0 : (PADL - t);

#pragma unroll
    for (int i = 0; i < 8; ++i) {
        const int row = r0 + i;
        const float* __restrict__ wp = wsm + ((size_t)row * HH + h) * KK;
        float w[KK];
#pragma unroll
        for (int k = 0; k < KK; ++k) w[k] = wp[k];

        vf4 acc = (vf4){0.f, 0.f, 0.f, 0.f};
        for (int k = kmin; k < KK; ++k) {
            const float4 xv =
                *(const float4*)(x + ((size_t)row + (size_t)(k - PADL) * BB) * CC + c);
            acc.x += w[k] * xv.x;
            acc.y += w[k] * xv.y;
            acc.z += w[k] * xv.z;
            acc.w += w[k] * xv.w;
        }
        __builtin_nontemporal_store(acc, (vf4*)(out + (size_t)row * CC + c));
    }
}

extern "C" void kernel_launch(void* const* d_in, const int* in_sizes, int n_in,
                              void* d_out, int out_size, void* d_ws, size_t ws_size,
                              hipStream_t stream) {
    const float* x = (const float*)d_in[0];   // (T, B, C)
    const float* W = (const float*)d_in[1];   // (H*K, C)
    float* out = (float*)d_out;                         // (T, B, C)
    float* dense = out + (size_t)TT * BB * CC;          // (B*H, T, T)
    float* wsm = (float*)d_ws;                          // (T, B, H, K) scratch

    k1_weights<<<(TT * BB) / 32, 128, 0, stream>>>(x, W, wsm);
    k2_dense<<<BB * HH * (TT / 16), 256, 0, stream>>>(wsm, dense);
    k3_out<<<(TT * BB) / 8, 256, 0, stream>>>(x, wsm, out);
}

// Round 4
// 1345.746 us; speedup vs baseline: 1.0130x; 1.0130x over previous
//
#include <hip/hip_runtime.h>
#include <math.h>

#define TT 1024
#define BB 16
#define CC 1024
#define HH 16
#define KK 7
#define PADL 6
#define HK 112        // H*K
#define WSTRIDE 68    // LDS row stride in floats: 272 B (16B-aligned)

// ---------------------------------------------------------------------------
// K1: logits = x @ W^T, band-masked softmax -> wsm[t,b,h,k].
// EXACT R2 structure (measured best): 256 threads, tx=tid&15 -> head
// (thread-local softmax), ty=tid>>4 -> row pair; 32 rows/block, grid 512.
// W staged per 64-channel chunk into LDS; reads are 16-distinct-address x
// 4-way-broadcast ds_read_b128 (broadcast lanes merge -> cheap).
// ---------------------------------------------------------------------------
__global__ __launch_bounds__(256) void k1_weights(const float* __restrict__ x,
                                                  const float* __restrict__ W,
                                                  float* __restrict__ wsm) {
    __shared__ float Wl[HK * WSTRIDE];   // 29.75 KB -> 2 blocks/CU, 8 waves/CU

    const int tid = threadIdx.x;
    const int tx = tid & 15;        // head
    const int ty = tid >> 4;        // 0..15
    const int row0 = blockIdx.x * 32 + ty * 2;   // (t*B + b) flat row

    const float* __restrict__ xr0 = x + (size_t)row0 * CC;
    const float* __restrict__ xr1 = xr0 + CC;

    float acc0[KK], acc1[KK];
#pragma unroll
    for (int k = 0; k < KK; ++k) { acc0[k] = 0.f; acc1[k] = 0.f; }

    for (int c0 = 0; c0 < CC; c0 += 64) {
        __syncthreads();   // previous chunk's reads done before overwrite
#pragma unroll
        for (int j = 0; j < 7; ++j) {
            const int i = j * 1024 + tid * 4;
            const int o = i >> 6;        // 0..111
            const int c = i & 63;        // float4-aligned
            const float4 v = *(const float4*)(W + (size_t)o * CC + c0 + c);
            *(float4*)(&Wl[o * WSTRIDE + c]) = v;
        }
        __syncthreads();

        const float* __restrict__ Wb = &Wl[(tx * KK) * WSTRIDE];
#pragma unroll 4
        for (int c = 0; c < 64; c += 4) {
            const float4 xv0 = *(const float4*)(xr0 + c0 + c);
            const float4 xv1 = *(const float4*)(xr1 + c0 + c);
#pragma unroll
            for (int k = 0; k < KK; ++k) {
                const float4 wv = *(const float4*)(Wb + k * WSTRIDE + c);
                acc0[k] += xv0.x * wv.x + xv0.y * wv.y + xv0.z * wv.z + xv0.w * wv.w;
                acc1[k] += xv1.x * wv.x + xv1.y * wv.y + xv1.z * wv.z + xv1.w * wv.w;
            }
        }
    }

#pragma unroll
    for (int i = 0; i < 2; ++i) {
        const float* a = (i == 0) ? acc0 : acc1;
        const int row = row0 + i;
        const int t = row >> 4;                    // row = t*B + b
        const int kmin = (t >= PADL) ? 0 : (PADL - t);

        float m = -INFINITY;
#pragma unroll
        for (int k = 0; k < KK; ++k)
            if (k >= kmin) m = fmaxf(m, a[k]);

        float e[KK];
        float s = 0.f;
#pragma unroll
        for (int k = 0; k < KK; ++k) {
            if (k >= kmin) { e[k] = expf(a[k] - m); s += e[k]; }
            else           { e[k] = 0.f; }
        }
        const float inv = 1.f / s;
        float* __restrict__ wp = wsm + (((size_t)row * HH) + tx) * KK;
#pragma unroll
        for (int k = 0; k < KK; ++k) wp[k] = e[k] * inv;
    }
}

// ---------------------------------------------------------------------------
// K23: fused dense-band writer + windowed weighted sum. 18432 blocks =
// 9 x 2048; every 9th block (rem==8) is an "out" block, the other 8 are
// dense blocks. The out blocks' L3-gather reads overlap the dense blocks'
// HBM write stream instead of serializing after it.
// ---------------------------------------------------------------------------
__global__ __launch_bounds__(256) void k23(const float* __restrict__ x,
                                           const float* __restrict__ wsm,
                                           float* __restrict__ out,
                                           float* __restrict__ dense) {
    const int blk = blockIdx.x;
    const int grp = blk / 9;            // 0..2047
    const int rem = blk - grp * 9;      // 0..8

    if (rem == 8) {
        // ---- out block: 8 (t,b) rows (all share t), 256 thr x float4 ----
        const int r0 = grp << 3;        // flat row = t*B + b
        const int t = r0 >> 4;
        const int c = threadIdx.x << 2;
        const int h = c >> 6;
        const int kmin = (t >= PADL) ? 0 : (PADL - t);

#pragma unroll
        for (int i = 0; i < 8; ++i) {
            const int row = r0 + i;
            const float* __restrict__ wp = wsm + ((size_t)row * HH + h) * KK;
            float w[KK];
#pragma unroll
            for (int k = 0; k < KK; ++k) w[k] = wp[k];

            float4 acc = make_float4(0.f, 0.f, 0.f, 0.f);
            for (int k = kmin; k < KK; ++k) {
                const float4 xv = *(const float4*)(
                    x + ((size_t)row + (size_t)(k - PADL) * BB) * CC + c);
                acc.x += w[k] * xv.x;
                acc.y += w[k] * xv.y;
                acc.z += w[k] * xv.z;
                acc.w += w[k] * xv.w;
            }
            *(float4*)(out + (size_t)row * CC + c) = acc;
        }
    } else {
        // ---- dense block: (bh, 16-row t-chunk), 64 KB contiguous ----
        const int kb = grp * 8 + rem;   // 0..16383
        const int bh = kb >> 6;
        const int tc = kb & 63;
        const int b = bh >> 4;
        const int h = bh & 15;

        const int col = threadIdx.x << 2;
        const int t0 = tc * 16;

        float* __restrict__ drow = dense + ((size_t)bh * TT + t0) * TT + col;

#pragma unroll
        for (int i = 0; i < 16; ++i) {
            const int t = t0 + i;
            const int lo = t - PADL;   // may be negative
            float4 v = make_float4(0.f, 0.f, 0.f, 0.f);
            if (col + 3 >= lo && col <= t) {
                const float* __restrict__ wp =
                    wsm + (((size_t)t * BB + b) * HH + h) * KK;
                float* pv = &v.x;
#pragma unroll
                for (int j = 0; j < 4; ++j) {
                    const int cc = col + j;
                    if (cc >= lo && cc <= t && cc >= 0) pv[j] = wp[cc - lo];
                }
            }
            *(float4*)drow = v;
            drow += TT;
        }
    }
}

extern "C" void kernel_launch(void* const* d_in, const int* in_sizes, int n_in,
                              void* d_out, int out_size, void* d_ws, size_t ws_size,
                              hipStream_t stream) {
    const float* x = (const float*)d_in[0];   // (T, B, C)
    const float* W = (const float*)d_in[1];   // (H*K, C)
    float* out = (float*)d_out;                         // (T, B, C)
    float* dense = out + (size_t)TT * BB * CC;          // (B*H, T, T)
    float* wsm = (float*)d_ws;                          // (T, B, H, K) scratch

    k1_weights<<<(TT * BB) / 32, 256, 0, stream>>>(x, W, wsm);
    k23<<<9 * 2048, 256, 0, stream>>>(x, wsm, out, dense);
}

// Round 6
// 1209.850 us; speedup vs baseline: 1.1267x; 1.1123x over previous
//
#include <hip/hip_runtime.h>
#include <math.h>

#define TT 1024
#define BB 16
#define CC 1024
#define HH 16
#define KK 7
#define PADL 6
#define HK 112          // H*K
#define LSTRIDE 116     // logits LDS row stride (floats)

typedef short bf16x8 __attribute__((ext_vector_type(8)));
typedef float f32x4 __attribute__((ext_vector_type(4)));

__device__ __forceinline__ short f2bf(float f) {
    union { float f; unsigned u; } v; v.f = f;
    unsigned r = v.u + 0x7fff + ((v.u >> 16) & 1);   // RNE; inputs finite
    return (short)(r >> 16);
}

// ---------------------------------------------------------------------------
// K0: W (112x1024 fp32) -> Wb (bf16). 114688 elems = 56 blocks x 256 thr x 8.
// ---------------------------------------------------------------------------
__global__ __launch_bounds__(256) void k0_cvtW(const float* __restrict__ W,
                                               short* __restrict__ Wb) {
    const int i = (blockIdx.x * 256 + threadIdx.x) * 8;
    const float4 a0 = *(const float4*)(W + i);
    const float4 a1 = *(const float4*)(W + i + 4);
    bf16x8 v;
    v[0] = f2bf(a0.x); v[1] = f2bf(a0.y); v[2] = f2bf(a0.z); v[3] = f2bf(a0.w);
    v[4] = f2bf(a1.x); v[5] = f2bf(a1.y); v[6] = f2bf(a1.z); v[7] = f2bf(a1.w);
    *(bf16x8*)(Wb + i) = v;
}

// ---------------------------------------------------------------------------
// K1: logits = x @ W^T via MFMA bf16 + band-masked softmax -> wsm.
// 256 blocks x 256 thr (4 waves); wave handles strip t = blk*4+w, rows
// (t, b=0..15). A = x rows cvt'd to bf16 (m=lane&15, k=quad*8+j);
// B = Wb rows (n=lane&15, k=quad*8+j), 7 N-tiles of 16.
// D layout is determined AT RUNTIME by a probe MFMA (A=I, B[k][n]=k):
// probe acc == quad*4+reg  -> claimed layout  (row=quad*4+reg, col=lane&15)
// probe acc == lane&15     -> transposed      (row=lane&15, col=quad*4+reg)
// The probe algebra is invariant to any shared A/B k-permutation.
// ---------------------------------------------------------------------------
__global__ __launch_bounds__(256) void k1_mfma(const float* __restrict__ x,
                                               const short* __restrict__ Wb,
                                               float* __restrict__ wsm) {
    __shared__ __align__(16) float Llog[4][16 * LSTRIDE];
    __shared__ __align__(16) float Lout[4][16 * HK];

    const int tid = threadIdx.x;
    const int w = tid >> 6;
    const int lane = tid & 63;
    const int quad = lane >> 4;
    const int lr = lane & 15;
    const int strip = blockIdx.x * 4 + w;     // = t
    const int r0 = strip * 16;                // flat (t*B+b) row base

    // ---- layout probe ----
    bf16x8 ap, bp;
#pragma unroll
    for (int e = 0; e < 8; ++e) {
        const int k = quad * 8 + e;
        ap[e] = (k == lr) ? (short)0x3F80 : (short)0;   // A = I (first 16 k)
        bp[e] = f2bf((float)k);                          // B[k][n] = k
    }
    f32x4 pz = (f32x4){0.f, 0.f, 0.f, 0.f};
    pz = __builtin_amdgcn_mfma_f32_16x16x32_bf16(ap, bp, pz, 0, 0, 0);
    const bool claim = (pz[0] == (float)(quad * 4)) &&
                       (pz[1] == (float)(quad * 4 + 1));

    // ---- main GEMM ----
    const float* __restrict__ xa = x + (size_t)(r0 + lr) * CC + quad * 8;
    const short* __restrict__ wb = Wb + (size_t)lr * CC + quad * 8;

    f32x4 acc[7];
#pragma unroll
    for (int j = 0; j < 7; ++j) acc[j] = (f32x4){0.f, 0.f, 0.f, 0.f};

#pragma unroll 4
    for (int k0 = 0; k0 < CC; k0 += 32) {
        const float4 a0 = *(const float4*)(xa + k0);
        const float4 a1 = *(const float4*)(xa + k0 + 4);
        bf16x8 af;
        af[0] = f2bf(a0.x); af[1] = f2bf(a0.y); af[2] = f2bf(a0.z); af[3] = f2bf(a0.w);
        af[4] = f2bf(a1.x); af[5] = f2bf(a1.y); af[6] = f2bf(a1.z); af[7] = f2bf(a1.w);
#pragma unroll
        for (int j = 0; j < 7; ++j) {
            const bf16x8 bfrag = *(const bf16x8*)(wb + (size_t)(j * 16) * CC + k0);
            acc[j] = __builtin_amdgcn_mfma_f32_16x16x32_bf16(af, bfrag, acc[j], 0, 0, 0);
        }
    }

    // ---- scatter D into LDS with runtime-selected mapping ----
    // claimed: value = logits[row=quad*4+r][col(tile)=lr]
    // transposed: value = logits[row=lr][col(tile)=quad*4+r]
#pragma unroll
    for (int j = 0; j < 7; ++j)
#pragma unroll
        for (int r = 0; r < 4; ++r) {
            const int rowi = claim ? (quad * 4 + r) : lr;
            const int coli = claim ? lr : (quad * 4 + r);
            Llog[w][rowi * LSTRIDE + j * 16 + coli] = acc[j][r];
        }
    __syncthreads();

    // ---- masked softmax: 256 (row,head) pairs per wave, 4 per lane ----
    const int kmin = (strip >= PADL) ? 0 : (PADL - strip);
#pragma unroll
    for (int p = 0; p < 4; ++p) {
        const int idx = p * 64 + lane;        // 0..255
        const int m = idx >> 4;
        const int h = idx & 15;
        const float* lp = &Llog[w][m * LSTRIDE + h * KK];
        float a[KK];
#pragma unroll
        for (int k = 0; k < KK; ++k) a[k] = lp[k];

        float mx = -INFINITY;
#pragma unroll
        for (int k = 0; k < KK; ++k)
            if (k >= kmin) mx = fmaxf(mx, a[k]);
        float e[KK], s = 0.f;
#pragma unroll
        for (int k = 0; k < KK; ++k) {
            if (k >= kmin) { e[k] = expf(a[k] - mx); s += e[k]; }
            else           { e[k] = 0.f; }
        }
        const float inv = 1.f / s;
        float* op = &Lout[w][m * HK + h * KK];
#pragma unroll
        for (int k = 0; k < KK; ++k) op[k] = e[k] * inv;
    }
    __syncthreads();

    // ---- coalesced copy-out: 1792 contiguous floats -> wsm + r0*112 ----
    float* __restrict__ dst = wsm + (size_t)r0 * HK;
    const float* __restrict__ src = &Lout[w][0];
#pragma unroll
    for (int i = 0; i < 7; ++i) {
        const int o = i * 256 + lane * 4;
        *(float4*)(dst + o) = *(const float4*)(src + o);
    }
}

// ---------------------------------------------------------------------------
// K2 (R2-exact): stream the full dense (B*H, T, T) band matrix. One block per
// (bh, 16-row t-chunk): 256 threads x 16 rows x float4 = 64 KB contiguous.
// grid = B*H*(T/16) = 16384 blocks.
// ---------------------------------------------------------------------------
__global__ __launch_bounds__(256) void k2_dense(const float* __restrict__ wsm,
                                                float* __restrict__ dense) {
    const int blk = blockIdx.x;        // bh*64 + tc
    const int bh = blk >> 6;
    const int tc = blk & 63;
    const int b = bh >> 4;
    const int h = bh & 15;

    const int col = threadIdx.x << 2;
    const int t0 = tc * 16;

    float* __restrict__ drow = dense + ((size_t)bh * TT + t0) * TT + col;

#pragma unroll
    for (int i = 0; i < 16; ++i) {
        const int t = t0 + i;
        const int lo = t - PADL;
        float4 v = make_float4(0.f, 0.f, 0.f, 0.f);
        if (col + 3 >= lo && col <= t) {
            const float* __restrict__ wp =
                wsm + (((size_t)t * BB + b) * HH + h) * KK;
            float* pv = &v.x;
#pragma unroll
            for (int j = 0; j < 4; ++j) {
                const int cc = col + j;
                if (cc >= lo && cc <= t && cc >= 0) pv[j] = wp[cc - lo];
            }
        }
        *(float4*)drow = v;
        drow += TT;
    }
}

// ---------------------------------------------------------------------------
// K3 (R2-exact): out[t,b,c] = sum_k wsm[t,b,h,k] * x[t+k-6, b, c], h = c/64.
// One block per 4 (t,b) rows (same t), 256 threads x float4. grid = 4096.
// ---------------------------------------------------------------------------
__global__ __launch_bounds__(256) void k3_out(const float* __restrict__ x,
                                              const float* __restrict__ wsm,
                                              float* __restrict__ out) {
    const int r0 = blockIdx.x << 2;
    const int t = r0 >> 4;
    const int c = threadIdx.x << 2;
    const int h = c >> 6;
    const int kmin = (t >= PADL) ? 0 : (PADL - t);

#pragma unroll
    for (int i = 0; i < 4; ++i) {
        const int row = r0 + i;
        const float* __restrict__ wp = wsm + ((size_t)row * HH + h) * KK;
        float w[KK];
#pragma unroll
        for (int k = 0; k < KK; ++k) w[k] = wp[k];

        float4 acc = make_float4(0.f, 0.f, 0.f, 0.f);
        for (int k = kmin; k < KK; ++k) {
            const float4 xv =
                *(const float4*)(x + ((size_t)row + (size_t)(k - PADL) * BB) * CC + c);
            acc.x += w[k] * xv.x;
            acc.y += w[k] * xv.y;
            acc.z += w[k] * xv.z;
            acc.w += w[k] * xv.w;
        }
        *(float4*)(out + (size_t)row * CC + c) = acc;
    }
}

extern "C" void kernel_launch(void* const* d_in, const int* in_sizes, int n_in,
                              void* d_out, int out_size, void* d_ws, size_t ws_size,
                              hipStream_t stream) {
    const float* x = (const float*)d_in[0];   // (T, B, C)
    const float* W = (const float*)d_in[1];   // (H*K, C)
    float* out = (float*)d_out;                         // (T, B, C)
    float* dense = out + (size_t)TT * BB * CC;          // (B*H, T, T)
    float* wsm = (float*)d_ws;                          // (T, B, H, K)
    short* Wb = (short*)(wsm + (size_t)TT * BB * HK);   // bf16 W, 229 KB

    k0_cvtW<<<56, 256, 0, stream>>>(W, Wb);
    k1_mfma<<<256, 256, 0, stream>>>(x, Wb, wsm);
    k2_dense<<<BB * HH * (TT / 16), 256, 0, stream>>>(wsm, dense);
    k3_out<<<(TT * BB) / 4, 256, 0, stream>>>(x, wsm, out);
}